// Round 1
// baseline (294.532 us; speedup 1.0000x reference)
//
#include <hip/hip_runtime.h>
#include <hip/hip_bf16.h>

typedef float f32x4 __attribute__((ext_vector_type(4)));
typedef short bf16x8 __attribute__((ext_vector_type(8)));

#define MFMA16(a, b, c) __builtin_amdgcn_mfma_f32_16x16x32_bf16(a, b, c, 0, 0, 0)

// Problem constants
constexpr int K1  = 940;    // IN_F
constexpr int KP2 = 1024;   // K padded to 8 chunks of 128
constexpr int NP  = 112;    // N=100 padded to 7 tiles of 16
constexpr int RS  = 116;    // red LDS row stride (floats): 4*RS%32==16 -> 2-way banks (free)
constexpr int OSL = 136;    // out_s LDS row stride (bf16): 272B -> 2-way banks

__device__ __forceinline__ float sigf(float x) { return 1.f / (1.f + __expf(-x)); }
__device__ __forceinline__ float tanhfast(float x) { return 2.f / (1.f + __expf(-2.f * x)) - 1.f; }

__device__ __forceinline__ short f2b(float x) {
  __hip_bfloat16 b = __float2bfloat16(x);
  return *reinterpret_cast<short*>(&b);
}

// ---------------------------------------------------------------------------
// Prep: fold swapaxes(-1,-2) into the weights, convert fp32->bf16, zero-pad.
// w2[n][k] (n<112, k<1024) = bf16(lin_w[n][f]), k=c10*94+c2*47+c47,
// f=c10*94+c47*2+c2; zero outside n<100,k<940.
// bw2[g][k] = bf16(b_wih[g][k]) zero-padded K 100->128.
// ---------------------------------------------------------------------------
__global__ void prep_kernel(const float* __restrict__ lin_w,
                            const float* __restrict__ b_wih,
                            __hip_bfloat16* __restrict__ w2,
                            __hip_bfloat16* __restrict__ bw2) {
  int idx = blockIdx.x * 256 + threadIdx.x;
  if (idx < NP * KP2) {
    int n = idx >> 10, k = idx & 1023;
    float v = 0.f;
    if (n < 100 && k < K1) {
      int c10 = k / 94, rem = k - c10 * 94;
      int c2 = rem / 47, c47 = rem - c2 * 47;
      int f = c10 * 94 + c47 * 2 + c2;
      v = lin_w[n * K1 + f];
    }
    w2[idx] = __float2bfloat16(v);
  } else {
    int i2 = idx - NP * KP2;
    if (i2 < 64 * 128) {
      int g = i2 >> 7, k = i2 & 127;
      bw2[i2] = __float2bfloat16((k < 100) ? b_wih[g * 100 + k] : 0.f);
    }
  }
}

// ---------------------------------------------------------------------------
// Mega-fused: linear+relu (split-K-8 MFMA, B in registers) -> xg GEMM (from
// LDS) -> beats LSTM (8 waves = 8 seqs, shfl recurrence). One block = 64 GEMM
// rows = 8 complete frac-sequences. out1/xg never touch HBM; only the 2 MB
// beats tensor is written.
// LDS diet: red (Phase A scratch) and xg_s (Phase B/C) are barrier-separated
// in time -> union them. 76800 B total => 2 blocks/CU (was 91648 => 1/CU).
// ---------------------------------------------------------------------------
__global__ __launch_bounds__(512, 4)
void fused_encoder(const float* __restrict__ ch,
                   const __hip_bfloat16* __restrict__ w2,
                   const float* __restrict__ lin_b,
                   const __hip_bfloat16* __restrict__ bw2,
                   const float* __restrict__ bih,
                   const float* __restrict__ bhh,
                   const float* __restrict__ whh,
                   float* __restrict__ beats) {
  // red:  8*16*RS floats = 59392 B  (Phase A only)
  // xg_s: 64*65 floats   = 16640 B  (Phase B/C only, aliases red)
  // out_s: 64*OSL bf16   = 17408 B  (Phase A out -> Phase B in)
  __shared__ __align__(16) char smem[8 * 16 * RS * 4 + 64 * OSL * 2];
  float* red  = reinterpret_cast<float*>(smem);
  float* xg_s = reinterpret_cast<float*>(smem);
  __hip_bfloat16* out_s = reinterpret_cast<__hip_bfloat16*>(smem + 8 * 16 * RS * 4);

  const int tid = threadIdx.x;
  const int w = tid >> 6, lane = tid & 63;
  const int l16 = lane & 15, bq = lane >> 4;
  const int kbase = w * 128;

  // ---- Phase A: split-K GEMM. B preload: 28 fragments in registers. ----
  bf16x8 breg[4][7];
#pragma unroll
  for (int s = 0; s < 4; ++s)
#pragma unroll
    for (int nt = 0; nt < 7; ++nt)
      breg[s][nt] = *reinterpret_cast<const bf16x8*>(
          &w2[(nt * 16 + l16) * KP2 + kbase + s * 32 + bq * 8]);

  const int mbase = blockIdx.x * 64;

  // Wave 7 (k 896..1023): s=0 vector, s=1 masked scalars (k<940), s=2,3 zero.
  auto issueA = [&](int m0, float4* buf) {
    const float* ar = ch + (long)(m0 + l16) * K1 + kbase + bq * 8;
    if (w < 7) {
#pragma unroll
      for (int s = 0; s < 4; ++s) {
        buf[2 * s]     = *reinterpret_cast<const float4*>(ar + s * 32);
        buf[2 * s + 1] = *reinterpret_cast<const float4*>(ar + s * 32 + 4);
      }
    } else {
      buf[0] = *reinterpret_cast<const float4*>(ar);
      buf[1] = *reinterpret_cast<const float4*>(ar + 4);
      float t[8];
#pragma unroll
      for (int j = 0; j < 8; ++j) {
        int k = 928 + bq * 8 + j;
        t[j] = (k < K1) ? ar[32 + j] : 0.f;
      }
      buf[2] = float4{t[0], t[1], t[2], t[3]};
      buf[3] = float4{t[4], t[5], t[6], t[7]};
      buf[4] = buf[5] = buf[6] = buf[7] = float4{0.f, 0.f, 0.f, 0.f};
    }
  };

  float4 a0[8], a1[8];
  issueA(mbase, a0);

#pragma unroll
  for (int i = 0; i < 4; ++i) {
    float4* cur = (i & 1) ? a1 : a0;
    float4* nxt = (i & 1) ? a0 : a1;
    if (i < 3) issueA(mbase + (i + 1) * 16, nxt);  // in flight during reduce

    f32x4 acc[7] = {};
#pragma unroll
    for (int s = 0; s < 4; ++s) {
      float4 lo = cur[2 * s], hi = cur[2 * s + 1];
      bf16x8 a = bf16x8{f2b(lo.x), f2b(lo.y), f2b(lo.z), f2b(lo.w),
                        f2b(hi.x), f2b(hi.y), f2b(hi.z), f2b(hi.w)};
#pragma unroll
      for (int nt = 0; nt < 7; ++nt) acc[nt] = MFMA16(a, breg[s][nt], acc[nt]);
    }

    // scatter partials: red[w][bq*4+r][nt*16+l16] (stride RS: 2-way banks)
#pragma unroll
    for (int nt = 0; nt < 7; ++nt)
#pragma unroll
      for (int r = 0; r < 4; ++r)
        red[(w * 16 + bq * 4 + r) * RS + nt * 16 + l16] = acc[nt][r];
    __syncthreads();

    // split-K reduce + bias + relu -> out_s (bf16, padded stride)
    if (tid < 448) {
      const int col = tid % NP;
      const int rb = (tid / NP) * 4;
      const float bias = (col < 100) ? lin_b[col] : 0.f;
#pragma unroll
      for (int r = 0; r < 4; ++r) {
        float s = 0.f;
#pragma unroll
        for (int ww = 0; ww < 8; ++ww) s += red[(ww * 16 + rb + r) * RS + col];
        float v = fmaxf(s + bias, 0.f);
        out_s[(i * 16 + rb + r) * OSL + col] = __float2bfloat16((col < 100) ? v : 0.f);
      }
    } else {
      const int t2 = tid - 448;               // zero K-pad cols 112..127
      const int row = t2 >> 2, c0 = 112 + (t2 & 3) * 4;
#pragma unroll
      for (int q = 0; q < 4; ++q)
        out_s[(i * 16 + row) * OSL + c0 + q] = __float2bfloat16(0.f);
    }
    __syncthreads();
  }

  // ---- Phase B: xg[64 rows][64 gates] = out_s @ bw2^T + (bih+bhh). ----
  // 16 (row-tile x gate-tile) combos over 8 waves: 2 gate-tiles each.
  // xg_s aliases red: safe, last red read was before the final barrier above.
  {
    const int rt = w >> 1, gt0 = (w & 1) * 2;
    bf16x8 av[4];
#pragma unroll
    for (int s = 0; s < 4; ++s)
      av[s] = *reinterpret_cast<const bf16x8*>(&out_s[(rt * 16 + l16) * OSL + s * 32 + bq * 8]);
    f32x4 xacc[2] = {{0.f, 0.f, 0.f, 0.f}, {0.f, 0.f, 0.f, 0.f}};
#pragma unroll
    for (int g2 = 0; g2 < 2; ++g2) {
      const int gt = gt0 + g2;
#pragma unroll
      for (int s = 0; s < 4; ++s) {
        bf16x8 b = *reinterpret_cast<const bf16x8*>(&bw2[(gt * 16 + l16) * 128 + s * 32 + bq * 8]);
        xacc[g2] = MFMA16(av[s], b, xacc[g2]);
      }
    }
#pragma unroll
    for (int g2 = 0; g2 < 2; ++g2) {
      const int gate = (gt0 + g2) * 16 + l16;
      const float bias = bih[gate] + bhh[gate];
#pragma unroll
      for (int r = 0; r < 4; ++r)
        xg_s[(rt * 16 + bq * 4 + r) * 65 + gate] = xacc[g2][r] + bias;
    }
  }
  __syncthreads();

  // ---- Phase C: beats LSTM. Wave w = sequence w (rows w*8..w*8+7). ----
  {
    const int cell = lane & 15;
    float wr[16];
#pragma unroll
    for (int u = 0; u < 16; ++u) wr[u] = whh[lane * 16 + u];
    float xv[8];
#pragma unroll
    for (int t = 0; t < 8; ++t) xv[t] = xg_s[(w * 8 + t) * 65 + lane];
    float h[16];
#pragma unroll
    for (int u = 0; u < 16; ++u) h[u] = 0.f;
    float c = 0.f;
    const int seq = blockIdx.x * 8 + w;
#pragma unroll
    for (int t = 0; t < 8; ++t) {
      float pre = xv[t];
#pragma unroll
      for (int u = 0; u < 16; ++u) pre += wr[u] * h[u];
      float act = (lane >= 32 && lane < 48) ? tanhfast(pre) : sigf(pre);
      float gi = __shfl(act, cell);
      float gf = __shfl(act, cell + 16);
      float gg = __shfl(act, cell + 32);
      float go = __shfl(act, cell + 48);
      c = gf * c + gi * gg;
      float hn = go * tanhfast(c);
#pragma unroll
      for (int u = 0; u < 16; ++u) h[u] = __shfl(hn, u);
      if (lane < 16) beats[seq * 128 + t * 16 + lane] = hn;
    }
  }
}

// ---------------------------------------------------------------------------
// Phase 3: bars biLSTM. 1024 seqs, T=4(beats), H=32. Block = 1 seq,
// 256 threads = 2 dirs x 128 gates. Reads last-frac beats h from d_out (fp32).
// fwd half -> cols 0..31, bwd half -> cols 32..63 (concat order).
// ---------------------------------------------------------------------------
__global__ __launch_bounds__(256)
void bars_bilstm(const float* __restrict__ fwih, const float* __restrict__ fwhh,
                 const float* __restrict__ fbih, const float* __restrict__ fbhh,
                 const float* __restrict__ rwih, const float* __restrict__ rwhh,
                 const float* __restrict__ rbih, const float* __restrict__ rbhh,
                 const float* __restrict__ beats,
                 float* __restrict__ bars) {
  const int tid = threadIdx.x;
  const int dir = tid >> 7, g = tid & 127;
  const int n = blockIdx.x;
  const float* wih = dir ? rwih : fwih;
  const float* whh = dir ? rwhh : fwhh;
  const float bias = dir ? (rbih[g] + rbhh[g]) : (fbih[g] + fbhh[g]);
  float wi[16], wh[32];
#pragma unroll
  for (int u = 0; u < 16; ++u) wi[u] = wih[g * 16 + u];
#pragma unroll
  for (int u = 0; u < 32; ++u) wh[u] = whh[g * 32 + u];
  __shared__ float xbuf[2][16];
  __shared__ float hbuf[2][32];
  __shared__ float gact[2][128];
  float c = 0.f;
  if (g < 32) hbuf[dir][g] = 0.f;
  __syncthreads();
  for (int t = 0; t < 4; ++t) {
    const int tt = dir ? (3 - t) : t;
    if (g < 16) xbuf[dir][g] = beats[((n * 4 + tt) * 8 + 7) * 16 + g];
    __syncthreads();
    float pre = bias;
#pragma unroll
    for (int u = 0; u < 16; ++u) pre += wi[u] * xbuf[dir][u];
#pragma unroll
    for (int u = 0; u < 32; ++u) pre += wh[u] * hbuf[dir][u];
    gact[dir][g] = (g >= 64 && g < 96) ? tanhfast(pre) : sigf(pre);
    __syncthreads();
    if (g < 32) {
      c = gact[dir][32 + g] * c + gact[dir][g] * gact[dir][64 + g];
      float hn = gact[dir][96 + g] * tanhfast(c);
      hbuf[dir][g] = hn;
      bars[(n * 4 + tt) * 64 + dir * 32 + g] = hn;
    }
    __syncthreads();
  }
}

extern "C" void kernel_launch(void* const* d_in, const int* in_sizes, int n_in,
                              void* d_out, int out_size, void* d_ws, size_t ws_size,
                              hipStream_t stream) {
  const float* ch    = (const float*)d_in[0];
  const float* lin_w = (const float*)d_in[1];
  const float* lin_b = (const float*)d_in[2];
  const float* b_wih = (const float*)d_in[3];
  const float* b_whh = (const float*)d_in[4];
  const float* b_bih = (const float*)d_in[5];
  const float* b_bhh = (const float*)d_in[6];
  const float* f_wih = (const float*)d_in[7];
  const float* f_whh = (const float*)d_in[8];
  const float* f_bih = (const float*)d_in[9];
  const float* f_bhh = (const float*)d_in[10];
  const float* r_wih = (const float*)d_in[11];
  const float* r_whh = (const float*)d_in[12];
  const float* r_bih = (const float*)d_in[13];
  const float* r_bhh = (const float*)d_in[14];

  char* ws = (char*)d_ws;
  __hip_bfloat16* w2  = (__hip_bfloat16*)ws;             // 112*1024*2 = 229376 B
  __hip_bfloat16* bw2 = (__hip_bfloat16*)(ws + 229376);  // 64*128*2   = 16384 B
  float*          out = (float*)d_out;

  prep_kernel<<<480, 256, 0, stream>>>(lin_w, b_wih, w2, bw2);
  fused_encoder<<<512, 512, 0, stream>>>(ch, w2, lin_b, bw2, b_bih, b_bhh,
                                         b_whh, out);
  bars_bilstm<<<1024, 256, 0, stream>>>(f_wih, f_whh, f_bih, f_bhh,
                                        r_wih, r_whh, r_bih, r_bhh,
                                        out, out + 524288);
}

// Round 2
// 239.036 us; speedup vs baseline: 1.2322x; 1.2322x over previous
//
#include <hip/hip_runtime.h>
#include <hip/hip_bf16.h>

typedef float f32x4 __attribute__((ext_vector_type(4)));
typedef short bf16x8 __attribute__((ext_vector_type(8)));

#define MFMA16(a, b, c) __builtin_amdgcn_mfma_f32_16x16x32_bf16(a, b, c, 0, 0, 0)

// Problem constants
constexpr int K1  = 940;    // IN_F
constexpr int KP2 = 1024;   // K padded to 8 chunks of 128
constexpr int NP  = 112;    // N=100 padded to 7 tiles of 16
constexpr int RS  = 116;    // red LDS row stride (floats): 4*RS%32==16 -> 2-way banks (free)
constexpr int OSL = 136;    // out_s LDS row stride (bf16): 272B -> 2-way banks

__device__ __forceinline__ float sigf(float x) { return 1.f / (1.f + __expf(-x)); }
__device__ __forceinline__ float tanhfast(float x) { return 2.f / (1.f + __expf(-2.f * x)) - 1.f; }

__device__ __forceinline__ short f2b(float x) {
  __hip_bfloat16 b = __float2bfloat16(x);
  return *reinterpret_cast<short*>(&b);
}

// ---------------------------------------------------------------------------
// Prep: fold swapaxes(-1,-2) into the weights, convert fp32->bf16, zero-pad.
// ---------------------------------------------------------------------------
__global__ void prep_kernel(const float* __restrict__ lin_w,
                            const float* __restrict__ b_wih,
                            __hip_bfloat16* __restrict__ w2,
                            __hip_bfloat16* __restrict__ bw2) {
  int idx = blockIdx.x * 256 + threadIdx.x;
  if (idx < NP * KP2) {
    int n = idx >> 10, k = idx & 1023;
    float v = 0.f;
    if (n < 100 && k < K1) {
      int c10 = k / 94, rem = k - c10 * 94;
      int c2 = rem / 47, c47 = rem - c2 * 47;
      int f = c10 * 94 + c47 * 2 + c2;
      v = lin_w[n * K1 + f];
    }
    w2[idx] = __float2bfloat16(v);
  } else {
    int i2 = idx - NP * KP2;
    if (i2 < 64 * 128) {
      int g = i2 >> 7, k = i2 & 127;
      bw2[i2] = __float2bfloat16((k < 100) ? b_wih[g * 100 + k] : 0.f);
    }
  }
}

// ---------------------------------------------------------------------------
// Mega-fused: linear+relu (split-K-8 MFMA, B in registers) -> xg GEMM (from
// LDS) -> beats LSTM (8 waves = 8 seqs, shfl recurrence). One block = 64 GEMM
// rows = 8 complete frac-sequences.
// LDS diet: red (Phase A scratch) and xg_s (Phase B/C) are barrier-separated
// in time -> union them. 76800 B total => 2 blocks/CU by LDS.
// launch_bounds (512, 2): compiler allocates 112 VGPR (no spill); 112 <= 128
// so HW still reaches 4 waves/SIMD = 2 blocks/CU. (512,4) forced 64 VGPR and
// 300 MB of scratch spill traffic -- never again.
// ---------------------------------------------------------------------------
__global__ __launch_bounds__(512, 2)
void fused_encoder(const float* __restrict__ ch,
                   const __hip_bfloat16* __restrict__ w2,
                   const float* __restrict__ lin_b,
                   const __hip_bfloat16* __restrict__ bw2,
                   const float* __restrict__ bih,
                   const float* __restrict__ bhh,
                   const float* __restrict__ whh,
                   float* __restrict__ beats) {
  // red:  8*16*RS floats = 59392 B  (Phase A only)
  // xg_s: 64*65 floats   = 16640 B  (Phase B/C only, aliases red)
  // out_s: 64*OSL bf16   = 17408 B  (Phase A out -> Phase B in)
  __shared__ __align__(16) char smem[8 * 16 * RS * 4 + 64 * OSL * 2];
  float* red  = reinterpret_cast<float*>(smem);
  float* xg_s = reinterpret_cast<float*>(smem);
  __hip_bfloat16* out_s = reinterpret_cast<__hip_bfloat16*>(smem + 8 * 16 * RS * 4);

  const int tid = threadIdx.x;
  const int w = tid >> 6, lane = tid & 63;
  const int l16 = lane & 15, bq = lane >> 4;
  const int kbase = w * 128;

  // ---- Phase A: split-K GEMM. B preload: 28 fragments in registers. ----
  bf16x8 breg[4][7];
#pragma unroll
  for (int s = 0; s < 4; ++s)
#pragma unroll
    for (int nt = 0; nt < 7; ++nt)
      breg[s][nt] = *reinterpret_cast<const bf16x8*>(
          &w2[(nt * 16 + l16) * KP2 + kbase + s * 32 + bq * 8]);

  const int mbase = blockIdx.x * 64;

  // Wave 7 (k 896..1023): s=0 vector, s=1 masked scalars (k<940), s=2,3 zero.
  auto issueA = [&](int m0, float4* buf) {
    const float* ar = ch + (long)(m0 + l16) * K1 + kbase + bq * 8;
    if (w < 7) {
#pragma unroll
      for (int s = 0; s < 4; ++s) {
        buf[2 * s]     = *reinterpret_cast<const float4*>(ar + s * 32);
        buf[2 * s + 1] = *reinterpret_cast<const float4*>(ar + s * 32 + 4);
      }
    } else {
      buf[0] = *reinterpret_cast<const float4*>(ar);
      buf[1] = *reinterpret_cast<const float4*>(ar + 4);
      float t[8];
#pragma unroll
      for (int j = 0; j < 8; ++j) {
        int k = 928 + bq * 8 + j;
        t[j] = (k < K1) ? ar[32 + j] : 0.f;
      }
      buf[2] = float4{t[0], t[1], t[2], t[3]};
      buf[3] = float4{t[4], t[5], t[6], t[7]};
      buf[4] = buf[5] = buf[6] = buf[7] = float4{0.f, 0.f, 0.f, 0.f};
    }
  };

  float4 a0[8], a1[8];
  issueA(mbase, a0);

#pragma unroll
  for (int i = 0; i < 4; ++i) {
    float4* cur = (i & 1) ? a1 : a0;
    float4* nxt = (i & 1) ? a0 : a1;
    if (i < 3) issueA(mbase + (i + 1) * 16, nxt);  // in flight during reduce

    f32x4 acc[7] = {};
#pragma unroll
    for (int s = 0; s < 4; ++s) {
      float4 lo = cur[2 * s], hi = cur[2 * s + 1];
      bf16x8 a = bf16x8{f2b(lo.x), f2b(lo.y), f2b(lo.z), f2b(lo.w),
                        f2b(hi.x), f2b(hi.y), f2b(hi.z), f2b(hi.w)};
#pragma unroll
      for (int nt = 0; nt < 7; ++nt) acc[nt] = MFMA16(a, breg[s][nt], acc[nt]);
    }

    // scatter partials: red[w][bq*4+r][nt*16+l16] (stride RS: 2-way banks)
#pragma unroll
    for (int nt = 0; nt < 7; ++nt)
#pragma unroll
      for (int r = 0; r < 4; ++r)
        red[(w * 16 + bq * 4 + r) * RS + nt * 16 + l16] = acc[nt][r];
    __syncthreads();

    // split-K reduce + bias + relu -> out_s (bf16, padded stride)
    if (tid < 448) {
      const int col = tid % NP;
      const int rb = (tid / NP) * 4;
      const float bias = (col < 100) ? lin_b[col] : 0.f;
#pragma unroll
      for (int r = 0; r < 4; ++r) {
        float s = 0.f;
#pragma unroll
        for (int ww = 0; ww < 8; ++ww) s += red[(ww * 16 + rb + r) * RS + col];
        float v = fmaxf(s + bias, 0.f);
        out_s[(i * 16 + rb + r) * OSL + col] = __float2bfloat16((col < 100) ? v : 0.f);
      }
    } else {
      const int t2 = tid - 448;               // zero K-pad cols 112..127
      const int row = t2 >> 2, c0 = 112 + (t2 & 3) * 4;
#pragma unroll
      for (int q = 0; q < 4; ++q)
        out_s[(i * 16 + row) * OSL + c0 + q] = __float2bfloat16(0.f);
    }
    __syncthreads();
  }

  // ---- Phase B: xg[64 rows][64 gates] = out_s @ bw2^T + (bih+bhh). ----
  // xg_s aliases red: safe, last red read was before the final barrier above.
  {
    const int rt = w >> 1, gt0 = (w & 1) * 2;
    bf16x8 av[4];
#pragma unroll
    for (int s = 0; s < 4; ++s)
      av[s] = *reinterpret_cast<const bf16x8*>(&out_s[(rt * 16 + l16) * OSL + s * 32 + bq * 8]);
    f32x4 xacc[2] = {{0.f, 0.f, 0.f, 0.f}, {0.f, 0.f, 0.f, 0.f}};
#pragma unroll
    for (int g2 = 0; g2 < 2; ++g2) {
      const int gt = gt0 + g2;
#pragma unroll
      for (int s = 0; s < 4; ++s) {
        bf16x8 b = *reinterpret_cast<const bf16x8*>(&bw2[(gt * 16 + l16) * 128 + s * 32 + bq * 8]);
        xacc[g2] = MFMA16(av[s], b, xacc[g2]);
      }
    }
#pragma unroll
    for (int g2 = 0; g2 < 2; ++g2) {
      const int gate = (gt0 + g2) * 16 + l16;
      const float bias = bih[gate] + bhh[gate];
#pragma unroll
      for (int r = 0; r < 4; ++r)
        xg_s[(rt * 16 + bq * 4 + r) * 65 + gate] = xacc[g2][r] + bias;
    }
  }
  __syncthreads();

  // ---- Phase C: beats LSTM. Wave w = sequence w (rows w*8..w*8+7). ----
  {
    const int cell = lane & 15;
    float wr[16];
#pragma unroll
    for (int u = 0; u < 16; ++u) wr[u] = whh[lane * 16 + u];
    float xv[8];
#pragma unroll
    for (int t = 0; t < 8; ++t) xv[t] = xg_s[(w * 8 + t) * 65 + lane];
    float h[16];
#pragma unroll
    for (int u = 0; u < 16; ++u) h[u] = 0.f;
    float c = 0.f;
    const int seq = blockIdx.x * 8 + w;
#pragma unroll
    for (int t = 0; t < 8; ++t) {
      float pre = xv[t];
#pragma unroll
      for (int u = 0; u < 16; ++u) pre += wr[u] * h[u];
      float act = (lane >= 32 && lane < 48) ? tanhfast(pre) : sigf(pre);
      float gi = __shfl(act, cell);
      float gf = __shfl(act, cell + 16);
      float gg = __shfl(act, cell + 32);
      float go = __shfl(act, cell + 48);
      c = gf * c + gi * gg;
      float hn = go * tanhfast(c);
#pragma unroll
      for (int u = 0; u < 16; ++u) h[u] = __shfl(hn, u);
      if (lane < 16) beats[seq * 128 + t * 16 + lane] = hn;
    }
  }
}

// ---------------------------------------------------------------------------
// Phase 3: bars biLSTM. 1024 seqs, T=4(beats), H=32. Block = 1 seq,
// 256 threads = 2 dirs x 128 gates.
// ---------------------------------------------------------------------------
__global__ __launch_bounds__(256)
void bars_bilstm(const float* __restrict__ fwih, const float* __restrict__ fwhh,
                 const float* __restrict__ fbih, const float* __restrict__ fbhh,
                 const float* __restrict__ rwih, const float* __restrict__ rwhh,
                 const float* __restrict__ rbih, const float* __restrict__ rbhh,
                 const float* __restrict__ beats,
                 float* __restrict__ bars) {
  const int tid = threadIdx.x;
  const int dir = tid >> 7, g = tid & 127;
  const int n = blockIdx.x;
  const float* wih = dir ? rwih : fwih;
  const float* whh = dir ? rwhh : fwhh;
  const float bias = dir ? (rbih[g] + rbhh[g]) : (fbih[g] + fbhh[g]);
  float wi[16], wh[32];
#pragma unroll
  for (int u = 0; u < 16; ++u) wi[u] = wih[g * 16 + u];
#pragma unroll
  for (int u = 0; u < 32; ++u) wh[u] = whh[g * 32 + u];
  __shared__ float xbuf[2][16];
  __shared__ float hbuf[2][32];
  __shared__ float gact[2][128];
  float c = 0.f;
  if (g < 32) hbuf[dir][g] = 0.f;
  __syncthreads();
  for (int t = 0; t < 4; ++t) {
    const int tt = dir ? (3 - t) : t;
    if (g < 16) xbuf[dir][g] = beats[((n * 4 + tt) * 8 + 7) * 16 + g];
    __syncthreads();
    float pre = bias;
#pragma unroll
    for (int u = 0; u < 16; ++u) pre += wi[u] * xbuf[dir][u];
#pragma unroll
    for (int u = 0; u < 32; ++u) pre += wh[u] * hbuf[dir][u];
    gact[dir][g] = (g >= 64 && g < 96) ? tanhfast(pre) : sigf(pre);
    __syncthreads();
    if (g < 32) {
      c = gact[dir][32 + g] * c + gact[dir][g] * gact[dir][64 + g];
      float hn = gact[dir][96 + g] * tanhfast(c);
      hbuf[dir][g] = hn;
      bars[(n * 4 + tt) * 64 + dir * 32 + g] = hn;
    }
    __syncthreads();
  }
}

extern "C" void kernel_launch(void* const* d_in, const int* in_sizes, int n_in,
                              void* d_out, int out_size, void* d_ws, size_t ws_size,
                              hipStream_t stream) {
  const float* ch    = (const float*)d_in[0];
  const float* lin_w = (const float*)d_in[1];
  const float* lin_b = (const float*)d_in[2];
  const float* b_wih = (const float*)d_in[3];
  const float* b_whh = (const float*)d_in[4];
  const float* b_bih = (const float*)d_in[5];
  const float* b_bhh = (const float*)d_in[6];
  const float* f_wih = (const float*)d_in[7];
  const float* f_whh = (const float*)d_in[8];
  const float* f_bih = (const float*)d_in[9];
  const float* f_bhh = (const float*)d_in[10];
  const float* r_wih = (const float*)d_in[11];
  const float* r_whh = (const float*)d_in[12];
  const float* r_bih = (const float*)d_in[13];
  const float* r_bhh = (const float*)d_in[14];

  char* ws = (char*)d_ws;
  __hip_bfloat16* w2  = (__hip_bfloat16*)ws;             // 112*1024*2 = 229376 B
  __hip_bfloat16* bw2 = (__hip_bfloat16*)(ws + 229376);  // 64*128*2   = 16384 B
  float*          out = (float*)d_out;

  prep_kernel<<<480, 256, 0, stream>>>(lin_w, b_wih, w2, bw2);
  fused_encoder<<<512, 512, 0, stream>>>(ch, w2, lin_b, bw2, b_bih, b_bhh,
                                         b_whh, out);
  bars_bilstm<<<1024, 256, 0, stream>>>(f_wih, f_whh, f_bih, f_bhh,
                                        r_wih, r_whh, r_bih, r_bhh,
                                        out, out + 524288);
}